// Round 1
// baseline (1152.765 us; speedup 1.0000x reference)
//
#include <hip/hip_runtime.h>

#define N_NODES 10000
#define N_EDGES 640000
#define DIM 128

// ---------------------------------------------------------------------------
// 1) xw = x @ W   (fp32, no MFMA on CDNA4 for fp32 -> vector ALU)
//    One block per node row; W columns read coalesced across threads,
//    x row staged in LDS. 328 MFLOP total - not the bottleneck.
// ---------------------------------------------------------------------------
__global__ void gemm_xw_kernel(const float* __restrict__ x,
                               const float* __restrict__ W,
                               float* __restrict__ xw) {
    __shared__ float xrow[DIM];
    const int row = blockIdx.x;
    const int c = threadIdx.x;
    xrow[c] = x[row * DIM + c];
    __syncthreads();
    float acc = 0.f;
#pragma unroll 8
    for (int k = 0; k < DIM; ++k)
        acc = fmaf(xrow[k], W[k * DIM + c], acc);
    xw[row * DIM + c] = acc;
}

// ---------------------------------------------------------------------------
// 2) degree over dst (self-loop added later as +1)
// ---------------------------------------------------------------------------
__global__ void deg_kernel(const int* __restrict__ dst, int* __restrict__ deg) {
    const int e = blockIdx.x * blockDim.x + threadIdx.x;
    if (e < N_EDGES) atomicAdd(&deg[dst[e]], 1);
}

__global__ void dinv_kernel(const int* __restrict__ deg, float* __restrict__ dinv) {
    const int v = blockIdx.x * blockDim.x + threadIdx.x;
    if (v < N_NODES) dinv[v] = rsqrtf((float)(deg[v] + 1));  // +1 = self-loop
}

// ---------------------------------------------------------------------------
// 3) scatter: 32 threads per edge, each thread owns 4 consecutive dims
//    (float4 gather of xw[src], 4 fp32 atomic adds into out[dst]).
// ---------------------------------------------------------------------------
__global__ void scatter_kernel(const int* __restrict__ src,
                               const int* __restrict__ dst,
                               const float* __restrict__ xw,
                               const float* __restrict__ dinv,
                               float* __restrict__ out) {
    const long long tid = (long long)blockIdx.x * blockDim.x + threadIdx.x;
    const int e = (int)(tid >> 5);
    const int lane4 = ((int)tid & 31) * 4;
    if (e >= N_EDGES) return;
    const int s = src[e];
    const int d = dst[e];
    const float norm = dinv[s] * dinv[d];
    const float4 v = *reinterpret_cast<const float4*>(&xw[s * DIM + lane4]);
    float* o = &out[d * DIM + lane4];
    atomicAdd(o + 0, v.x * norm);
    atomicAdd(o + 1, v.y * norm);
    atomicAdd(o + 2, v.z * norm);
    atomicAdd(o + 3, v.w * norm);
}

// ---------------------------------------------------------------------------
// 4) finalize: out = relu(out + xw[v]*dinv[v]^2 + b[c])   (self-loop + bias)
// ---------------------------------------------------------------------------
__global__ void finalize_kernel(float* __restrict__ out,
                                const float* __restrict__ xw,
                                const float* __restrict__ dinv,
                                const float* __restrict__ b) {
    const int i = blockIdx.x * blockDim.x + threadIdx.x;
    if (i >= N_NODES * DIM) return;
    const int v = i >> 7;
    const int c = i & (DIM - 1);
    const float di = dinv[v];
    const float val = out[i] + xw[i] * di * di + b[c];
    out[i] = fmaxf(val, 0.f);
}

extern "C" void kernel_launch(void* const* d_in, const int* in_sizes, int n_in,
                              void* d_out, int out_size, void* d_ws, size_t ws_size,
                              hipStream_t stream) {
    const float* x   = (const float*)d_in[0];
    const int*   ei  = (const int*)d_in[1];   // [2, E] int32 (JAX x64-off demotes int64)
    const float* W   = (const float*)d_in[2];
    const float* b   = (const float*)d_in[3];
    float* out = (float*)d_out;

    // workspace layout
    float* xw   = (float*)d_ws;                      // N*DIM floats = 5.12 MB
    int*   deg  = (int*)(xw + N_NODES * DIM);        // N ints
    float* dinv = (float*)(deg + N_NODES);           // N floats

    const int* src = ei;
    const int* dst = ei + N_EDGES;

    hipMemsetAsync(deg, 0, N_NODES * sizeof(int), stream);
    hipMemsetAsync(d_out, 0, (size_t)N_NODES * DIM * sizeof(float), stream);

    gemm_xw_kernel<<<N_NODES, DIM, 0, stream>>>(x, W, xw);
    deg_kernel<<<(N_EDGES + 255) / 256, 256, 0, stream>>>(dst, deg);
    dinv_kernel<<<(N_NODES + 255) / 256, 256, 0, stream>>>(deg, dinv);

    const long long scatter_threads = (long long)N_EDGES * 32;
    scatter_kernel<<<(int)((scatter_threads + 255) / 256), 256, 0, stream>>>(
        src, dst, xw, dinv, out);

    finalize_kernel<<<(N_NODES * DIM + 255) / 256, 256, 0, stream>>>(out, xw, dinv, b);
}

// Round 2
// 183.266 us; speedup vs baseline: 6.2901x; 6.2901x over previous
//
#include <hip/hip_runtime.h>

#define N_NODES 10000
#define N_EDGES 640000
#define DIM 128
#define GEMM_ROWS 16

// ---------------------------------------------------------------------------
// 1) degree over dst (self-loop accounted as +1 in dinv)
// ---------------------------------------------------------------------------
__global__ void deg_kernel(const int* __restrict__ dst, int* __restrict__ deg) {
    const int e = blockIdx.x * blockDim.x + threadIdx.x;
    if (e < N_EDGES) atomicAdd(&deg[dst[e]], 1);
}

__global__ void dinv_kernel(const int* __restrict__ deg, float* __restrict__ dinv) {
    const int v = blockIdx.x * blockDim.x + threadIdx.x;
    if (v < N_NODES) dinv[v] = rsqrtf((float)(deg[v] + 1));  // +1 = self-loop
}

// ---------------------------------------------------------------------------
// 2) xws = (x @ W) * dinv[row]   — 16-row tile in LDS, 16x register reuse of W
// ---------------------------------------------------------------------------
__global__ void gemm_xw_kernel(const float* __restrict__ x,
                               const float* __restrict__ W,
                               const float* __restrict__ dinv,
                               float* __restrict__ xws) {
    __shared__ float xs[GEMM_ROWS][DIM];
    const int c = threadIdx.x;          // 0..127 (output column)
    const int r0 = blockIdx.x * GEMM_ROWS;
#pragma unroll
    for (int i = 0; i < GEMM_ROWS; ++i)
        xs[i][c] = x[(r0 + i) * DIM + c];
    __syncthreads();

    float acc[GEMM_ROWS];
#pragma unroll
    for (int i = 0; i < GEMM_ROWS; ++i) acc[i] = 0.f;

    for (int k = 0; k < DIM; ++k) {
        const float w = W[k * DIM + c];
#pragma unroll
        for (int i = 0; i < GEMM_ROWS; ++i)
            acc[i] = fmaf(xs[i][k], w, acc[i]);   // xs[i][k]: LDS broadcast
    }
#pragma unroll
    for (int i = 0; i < GEMM_ROWS; ++i)
        xws[(r0 + i) * DIM + c] = acc[i] * dinv[r0 + i];
}

// ---------------------------------------------------------------------------
// 3) exclusive scan of deg -> row_ptr (and fill cursor copy). Single block.
// ---------------------------------------------------------------------------
__global__ void scan_kernel(const int* __restrict__ deg,
                            int* __restrict__ row_ptr,
                            int* __restrict__ fill) {
    __shared__ int buf[256];
    const int tid = threadIdx.x;
    int offset = 0;
    for (int base = 0; base < N_NODES; base += 256) {
        const int idx = base + tid;
        const int v = (idx < N_NODES) ? deg[idx] : 0;
        buf[tid] = v;
        __syncthreads();
#pragma unroll
        for (int s = 1; s < 256; s <<= 1) {
            const int t = (tid >= s) ? buf[tid - s] : 0;
            __syncthreads();
            buf[tid] += t;
            __syncthreads();
        }
        const int excl = buf[tid] - v + offset;
        if (idx < N_NODES) {
            row_ptr[idx] = excl;
            fill[idx] = excl;
        }
        offset += buf[255];
        __syncthreads();   // protect buf before next chunk overwrites
    }
    if (tid == 0) row_ptr[N_NODES] = offset;  // == N_EDGES
}

// ---------------------------------------------------------------------------
// 4) counting-sort edges by dst: ssrc[row_ptr[d] ...] = src list of node d
// ---------------------------------------------------------------------------
__global__ void csr_fill_kernel(const int* __restrict__ src,
                                const int* __restrict__ dst,
                                int* __restrict__ fill,
                                int* __restrict__ ssrc) {
    const int e = blockIdx.x * blockDim.x + threadIdx.x;
    if (e < N_EDGES) {
        const int d = dst[e];
        const int pos = atomicAdd(&fill[d], 1);
        ssrc[pos] = src[e];
    }
}

// ---------------------------------------------------------------------------
// 5) aggregate: one wave per node. out[v] = relu((sum xws[s] + xws[v])*dinv[v] + b)
//    Each lane owns 2 dims (float2, 8 B/lane -> 512 B coalesced per row read).
// ---------------------------------------------------------------------------
__global__ void __launch_bounds__(64)
aggregate_kernel(const int* __restrict__ row_ptr,
                 const int* __restrict__ ssrc,
                 const float* __restrict__ xws,
                 const float* __restrict__ dinv,
                 const float* __restrict__ b,
                 float* __restrict__ out) {
    const int v = blockIdx.x;
    const int c2 = threadIdx.x * 2;
    const int beg = row_ptr[v];
    const int end = row_ptr[v + 1];

    float ax = 0.f, ay = 0.f;
    int j = beg;
    for (; j + 3 < end; j += 4) {
        const int s0 = ssrc[j], s1 = ssrc[j + 1], s2 = ssrc[j + 2], s3 = ssrc[j + 3];
        const float2 v0 = *reinterpret_cast<const float2*>(&xws[s0 * DIM + c2]);
        const float2 v1 = *reinterpret_cast<const float2*>(&xws[s1 * DIM + c2]);
        const float2 v2 = *reinterpret_cast<const float2*>(&xws[s2 * DIM + c2]);
        const float2 v3 = *reinterpret_cast<const float2*>(&xws[s3 * DIM + c2]);
        ax += v0.x + v1.x + v2.x + v3.x;
        ay += v0.y + v1.y + v2.y + v3.y;
    }
    for (; j < end; ++j) {
        const int s = ssrc[j];
        const float2 vv = *reinterpret_cast<const float2*>(&xws[s * DIM + c2]);
        ax += vv.x;
        ay += vv.y;
    }
    // self-loop term: xws[v] already scaled by dinv[v]
    const float2 xv = *reinterpret_cast<const float2*>(&xws[v * DIM + c2]);
    ax += xv.x;
    ay += xv.y;

    const float dv = dinv[v];
    const float2 bb = *reinterpret_cast<const float2*>(&b[c2]);
    float2 o;
    o.x = fmaxf(fmaf(ax, dv, bb.x), 0.f);
    o.y = fmaxf(fmaf(ay, dv, bb.y), 0.f);
    *reinterpret_cast<float2*>(&out[v * DIM + c2]) = o;
}

extern "C" void kernel_launch(void* const* d_in, const int* in_sizes, int n_in,
                              void* d_out, int out_size, void* d_ws, size_t ws_size,
                              hipStream_t stream) {
    const float* x  = (const float*)d_in[0];
    const int*   ei = (const int*)d_in[1];   // [2, E] int32
    const float* W  = (const float*)d_in[2];
    const float* b  = (const float*)d_in[3];
    float* out = (float*)d_out;

    // workspace layout (16 B aligned chunks)
    float* xws     = (float*)d_ws;                    // N*DIM floats  (5.12 MB)
    int*   deg     = (int*)(xws + N_NODES * DIM);     // 10016 ints
    float* dinv    = (float*)(deg + 10016);           // 10016 floats
    int*   row_ptr = (int*)(dinv + 10016);            // 10016 ints (incl. [N])
    int*   fill    = row_ptr + 10016;                 // 10016 ints
    int*   ssrc    = fill + 10016;                    // E ints (2.56 MB)

    const int* src = ei;
    const int* dst = ei + N_EDGES;

    hipMemsetAsync(deg, 0, N_NODES * sizeof(int), stream);

    deg_kernel<<<(N_EDGES + 255) / 256, 256, 0, stream>>>(dst, deg);
    dinv_kernel<<<(N_NODES + 255) / 256, 256, 0, stream>>>(deg, dinv);
    gemm_xw_kernel<<<N_NODES / GEMM_ROWS, DIM, 0, stream>>>(x, W, dinv, xws);
    scan_kernel<<<1, 256, 0, stream>>>(deg, row_ptr, fill);
    csr_fill_kernel<<<(N_EDGES + 255) / 256, 256, 0, stream>>>(src, dst, fill, ssrc);
    aggregate_kernel<<<N_NODES, 64, 0, stream>>>(row_ptr, ssrc, xws, dinv, b, out);
}

// Round 3
// 148.495 us; speedup vs baseline: 7.7630x; 1.2342x over previous
//
#include <hip/hip_runtime.h>

#define N_NODES 10000
#define N_EDGES 640000
#define DIM 128
#define GEMM_ROWS 16

// ---------------------------------------------------------------------------
// 1) degree over dst (self-loop accounted as +1 in dinv). int4 = 4 edges/thread.
// ---------------------------------------------------------------------------
__global__ void deg_kernel(const int* __restrict__ dst, int* __restrict__ deg) {
    const int t = blockIdx.x * blockDim.x + threadIdx.x;
    if (t < N_EDGES / 4) {
        const int4 d4 = reinterpret_cast<const int4*>(dst)[t];
        atomicAdd(&deg[d4.x], 1);
        atomicAdd(&deg[d4.y], 1);
        atomicAdd(&deg[d4.z], 1);
        atomicAdd(&deg[d4.w], 1);
    }
}

// ---------------------------------------------------------------------------
// 2) exclusive scan of deg -> row_ptr + fill cursor + dinv, single block,
//    16 waves, shuffle-based (3 barriers per 1024-chunk).
// ---------------------------------------------------------------------------
__global__ void __launch_bounds__(1024)
scan_kernel(const int* __restrict__ deg,
            float* __restrict__ dinv,
            int* __restrict__ row_ptr,
            int* __restrict__ fill) {
    __shared__ int wsum[16];
    __shared__ int chunk_total;
    const int tid = threadIdx.x;
    const int lane = tid & 63;
    const int wid = tid >> 6;
    int offset = 0;
    for (int base = 0; base < N_NODES; base += 1024) {
        const int idx = base + tid;
        const int v = (idx < N_NODES) ? deg[idx] : 0;
        // intra-wave inclusive scan
        int sc = v;
#pragma unroll
        for (int s = 1; s < 64; s <<= 1) {
            const int t = __shfl_up(sc, s, 64);
            if (lane >= s) sc += t;
        }
        if (lane == 63) wsum[wid] = sc;
        __syncthreads();
        if (wid == 0) {
            const int w = (lane < 16) ? wsum[lane] : 0;
            int ws = w;
#pragma unroll
            for (int s = 1; s < 16; s <<= 1) {
                const int t = __shfl_up(ws, s, 64);
                if (lane >= s) ws += t;
            }
            if (lane == 15) chunk_total = ws;
            if (lane < 16) wsum[lane] = ws - w;  // exclusive wave offset
        }
        __syncthreads();
        const int excl = sc - v + wsum[wid] + offset;
        if (idx < N_NODES) {
            row_ptr[idx] = excl;
            fill[idx] = excl;
            dinv[idx] = rsqrtf((float)(v + 1));  // +1 = self-loop
        }
        offset += chunk_total;
        __syncthreads();  // protect wsum/chunk_total before next chunk
    }
    if (tid == 0) row_ptr[N_NODES] = offset;  // == N_EDGES
}

// ---------------------------------------------------------------------------
// 3) xws = (x @ W) * dinv[row]   — 16-row tile in LDS, 16x register reuse of W
// ---------------------------------------------------------------------------
__global__ void gemm_xw_kernel(const float* __restrict__ x,
                               const float* __restrict__ W,
                               const float* __restrict__ dinv,
                               float* __restrict__ xws) {
    __shared__ float xs[GEMM_ROWS][DIM];
    const int c = threadIdx.x;          // 0..127 (output column)
    const int r0 = blockIdx.x * GEMM_ROWS;
#pragma unroll
    for (int i = 0; i < GEMM_ROWS; ++i)
        xs[i][c] = x[(r0 + i) * DIM + c];
    __syncthreads();

    float acc[GEMM_ROWS];
#pragma unroll
    for (int i = 0; i < GEMM_ROWS; ++i) acc[i] = 0.f;

    for (int k = 0; k < DIM; ++k) {
        const float w = W[k * DIM + c];
#pragma unroll
        for (int i = 0; i < GEMM_ROWS; ++i)
            acc[i] = fmaf(xs[i][k], w, acc[i]);   // xs[i][k]: LDS broadcast
    }
#pragma unroll
    for (int i = 0; i < GEMM_ROWS; ++i)
        xws[(r0 + i) * DIM + c] = acc[i] * dinv[r0 + i];
}

// ---------------------------------------------------------------------------
// 4) counting-sort edges by dst: ssrc[row_ptr[d]...] = src list. 4 edges/thread.
// ---------------------------------------------------------------------------
__global__ void csr_fill_kernel(const int* __restrict__ src,
                                const int* __restrict__ dst,
                                int* __restrict__ fill,
                                int* __restrict__ ssrc) {
    const int t = blockIdx.x * blockDim.x + threadIdx.x;
    if (t < N_EDGES / 4) {
        const int4 s4 = reinterpret_cast<const int4*>(src)[t];
        const int4 d4 = reinterpret_cast<const int4*>(dst)[t];
        ssrc[atomicAdd(&fill[d4.x], 1)] = s4.x;
        ssrc[atomicAdd(&fill[d4.y], 1)] = s4.y;
        ssrc[atomicAdd(&fill[d4.z], 1)] = s4.z;
        ssrc[atomicAdd(&fill[d4.w], 1)] = s4.w;
    }
}

// ---------------------------------------------------------------------------
// 5) aggregate: one wave per node. out[v] = relu((sum xws[s] + xws[v])*dinv[v] + b)
//    Lane owns 2 dims (float2 -> 512 B coalesced row read); ssrc reads are
//    wave-uniform -> scalar loads.
// ---------------------------------------------------------------------------
__global__ void __launch_bounds__(64)
aggregate_kernel(const int* __restrict__ row_ptr,
                 const int* __restrict__ ssrc,
                 const float* __restrict__ xws,
                 const float* __restrict__ dinv,
                 const float* __restrict__ b,
                 float* __restrict__ out) {
    const int v = blockIdx.x;
    const int c2 = threadIdx.x * 2;
    const int beg = row_ptr[v];
    const int end = row_ptr[v + 1];

    float ax = 0.f, ay = 0.f;
    int j = beg;
    for (; j + 3 < end; j += 4) {
        const int s0 = ssrc[j], s1 = ssrc[j + 1], s2 = ssrc[j + 2], s3 = ssrc[j + 3];
        const float2 v0 = *reinterpret_cast<const float2*>(&xws[s0 * DIM + c2]);
        const float2 v1 = *reinterpret_cast<const float2*>(&xws[s1 * DIM + c2]);
        const float2 v2 = *reinterpret_cast<const float2*>(&xws[s2 * DIM + c2]);
        const float2 v3 = *reinterpret_cast<const float2*>(&xws[s3 * DIM + c2]);
        ax += v0.x + v1.x + v2.x + v3.x;
        ay += v0.y + v1.y + v2.y + v3.y;
    }
    for (; j < end; ++j) {
        const int s = ssrc[j];
        const float2 vv = *reinterpret_cast<const float2*>(&xws[s * DIM + c2]);
        ax += vv.x;
        ay += vv.y;
    }
    // self-loop term: xws[v] already scaled by dinv[v]
    const float2 xv = *reinterpret_cast<const float2*>(&xws[v * DIM + c2]);
    ax += xv.x;
    ay += xv.y;

    const float dv = dinv[v];
    const float2 bb = *reinterpret_cast<const float2*>(&b[c2]);
    float2 o;
    o.x = fmaxf(fmaf(ax, dv, bb.x), 0.f);
    o.y = fmaxf(fmaf(ay, dv, bb.y), 0.f);
    *reinterpret_cast<float2*>(&out[v * DIM + c2]) = o;
}

extern "C" void kernel_launch(void* const* d_in, const int* in_sizes, int n_in,
                              void* d_out, int out_size, void* d_ws, size_t ws_size,
                              hipStream_t stream) {
    const float* x  = (const float*)d_in[0];
    const int*   ei = (const int*)d_in[1];   // [2, E] int32
    const float* W  = (const float*)d_in[2];
    const float* b  = (const float*)d_in[3];
    float* out = (float*)d_out;

    // workspace layout (16 B aligned chunks)
    float* xws     = (float*)d_ws;                    // N*DIM floats  (5.12 MB)
    int*   deg     = (int*)(xws + N_NODES * DIM);     // 10016 ints
    float* dinv    = (float*)(deg + 10016);           // 10016 floats
    int*   row_ptr = (int*)(dinv + 10016);            // 10016 ints (incl. [N])
    int*   fill    = row_ptr + 10016;                 // 10016 ints
    int*   ssrc    = fill + 10016;                    // E ints (2.56 MB)

    const int* src = ei;
    const int* dst = ei + N_EDGES;

    hipMemsetAsync(deg, 0, N_NODES * sizeof(int), stream);

    deg_kernel<<<(N_EDGES / 4 + 255) / 256, 256, 0, stream>>>(dst, deg);
    scan_kernel<<<1, 1024, 0, stream>>>(deg, dinv, row_ptr, fill);
    gemm_xw_kernel<<<N_NODES / GEMM_ROWS, DIM, 0, stream>>>(x, W, dinv, xws);
    csr_fill_kernel<<<(N_EDGES / 4 + 255) / 256, 256, 0, stream>>>(src, dst, fill, ssrc);
    aggregate_kernel<<<N_NODES, 64, 0, stream>>>(row_ptr, ssrc, xws, dinv, b, out);
}